// Round 7
// baseline (158.274 us; speedup 1.0000x reference)
//
#include <hip/hip_runtime.h>
#include <hip/hip_bf16.h>

// Block-diagonal matmul: out[t, n*64+e] = sum_d inp[t, n*64+d] * blocks[n, d, e]
// T=16384, 64 blocks of 64x64, fp32 in/out, bf16 MFMA compute.
//
// Round 7: max-TLP design. R5/R6 proved the register allocator will not hold a
// deep per-wave pipeline (VGPR 52/64 vs ~115 needed). Flip regimes: make each
// wave tiny and run 32 waves/CU (m13-copy regime, TLP-provided MLP).
//  - split each block's OUTPUT cols across 2 waves (halves): weights 16 regs,
//    acc 8, MFMA 4/strip. Loads unchanged (both halves need all k; halves are
//    in the SAME WG -> same CU -> L1 dedups the duplicate row reads).
//  - zero LDS, zero barriers, unroll 1; peak live VGPR ~56.
//  - __launch_bounds__(256,8): VGPR cap 64 -> 8 WGs/CU = 2048 thr (CU cap).
//  - grid 2048 WGs = exactly 8/CU, single uniform round.
// WG b: n = b>>5, slot-pair p = b&31; wave w: slot = 2p + (w>>1), half = w&1;
// strips = slot + 64k, k=0..15.

typedef __attribute__((ext_vector_type(8))) short short8;   // 8 bf16
typedef __attribute__((ext_vector_type(4))) float f32x4;

#define D_TOT 4096
#define NK    16
#define STEP  ((size_t)64 * 16 * D_TOT)   // 64 strip-slots * 16 rows * 4096

__device__ __forceinline__ short f2b(float x) {
    union { __hip_bfloat16 h; short s; } u;
    u.h = __float2bfloat16(x);
    return u.s;
}

__device__ __forceinline__ short8 cvt8(f32x4 lo, f32x4 hi) {
    short8 a;
    a[0]=f2b(lo[0]); a[1]=f2b(lo[1]); a[2]=f2b(lo[2]); a[3]=f2b(lo[3]);
    a[4]=f2b(hi[0]); a[5]=f2b(hi[1]); a[6]=f2b(hi[2]); a[7]=f2b(hi[3]);
    return a;
}

__global__ __launch_bounds__(256, 8) void block_linear_kernel(
    const float* __restrict__ inp,
    const float* __restrict__ blocks,
    float* __restrict__ out)
{
    const int tid  = threadIdx.x;
    const int w    = tid >> 6;          // wave in WG
    const int lane = tid & 63;
    const int g    = lane >> 4;         // k-group
    const int lr   = lane & 15;         // row-within-strip / e-frag index

    const int n    = blockIdx.x >> 5;             // block (32 WGs per block)
    const int slot = ((blockIdx.x & 31) << 1) + (w >> 1);   // 0..63
    const int h    = w & 1;                        // output-col half

    // ---- half-block weights -> 16 VGPRs (one-time gather; L2/L3-hot) ----
    // frag (nt,s): lane (g,lr) holds W[d = s*32+8g+i][e = h*32 + nt*16 + lr]
    const float* Wn = blocks + (size_t)n * 4096;
    short8 wf[2][2];
    #pragma unroll
    for (int nt = 0; nt < 2; ++nt)
        #pragma unroll
        for (int s = 0; s < 2; ++s) {
            short8 a;
            #pragma unroll
            for (int i = 0; i < 8; ++i)
                a[i] = f2b(Wn[(s * 32 + 8 * g + i) * 64 + h * 32 + nt * 16 + lr]);
            wf[nt][s] = a;
        }

    const float* gin = inp + (size_t)(slot * 16 + lr) * D_TOT + n * 64 + 8 * g;
    float*      gout = out + (size_t)(slot * 16 + lr) * D_TOT + n * 64 + h * 32 + g * 4;

    #pragma unroll 1
    for (int k = 0; k < NK; ++k) {
        const float* p = gin + (size_t)k * STEP;
        f32x4 a0 = *(const f32x4*)(p);
        f32x4 a1 = *(const f32x4*)(p + 4);
        f32x4 a2 = *(const f32x4*)(p + 32);
        f32x4 a3 = *(const f32x4*)(p + 36);

        short8 b0 = cvt8(a0, a1);       // k = 0..31 of this lane's row
        short8 b1 = cvt8(a2, a3);       // k = 32..63

        float* go = gout + (size_t)k * STEP;
        #pragma unroll
        for (int nt = 0; nt < 2; ++nt) {
            f32x4 acc = (f32x4){0.f, 0.f, 0.f, 0.f};
            acc = __builtin_amdgcn_mfma_f32_16x16x32_bf16(wf[nt][0], b0, acc, 0, 0, 0);
            acc = __builtin_amdgcn_mfma_f32_16x16x32_bf16(wf[nt][1], b1, acc, 0, 0, 0);
            *(f32x4*)(go + nt * 16) = acc;   // cols h*32 + nt*16 + g*4 + j
        }
    }
}

extern "C" void kernel_launch(void* const* d_in, const int* in_sizes, int n_in,
                              void* d_out, int out_size, void* d_ws, size_t ws_size,
                              hipStream_t stream) {
    const float* inp    = (const float*)d_in[0];
    const float* blocks = (const float*)d_in[1];
    float* out          = (float*)d_out;

    block_linear_kernel<<<2048, 256, 0, stream>>>(inp, blocks, out);
}

// Round 8
// 116.804 us; speedup vs baseline: 1.3550x; 1.3550x over previous
//
#include <hip/hip_runtime.h>
#include <hip/hip_bf16.h>

// Block-diagonal matmul: out[t, n*64+e] = sum_d inp[t, n*64+d] * blocks[n, d, e]
// T=16384, 64 blocks of 64x64, fp32 in/out, bf16 MFMA compute.
//
// Round 8: byte-reduction via non-temporal stores (L3 churn fix).
//  Diagnosis: all rounds sit at dur = (FETCH+WRITE)/~2.9 TB/s; occupancy (R7),
//  contiguity (R3), ILP (R5/R6) all falsified as levers. Input(268MB) +
//  output(268MB) > L3(256MB): output allocation evicts input, forcing ~50% of
//  reads to HBM (FETCH ~138MB). Output has zero reuse -> NT stores (LLC
//  no-allocate) keep input L3-resident: FETCH -> small, HBM ~= writes only.
//  Structure: R6 (full-block waves, no read dup), no pipeline games, unroll 1.
//  4096 waves: wave wid -> block n = wid/64, strips (wid%64)+64k, k=0..15.

typedef __attribute__((ext_vector_type(8))) short short8;   // 8 bf16
typedef __attribute__((ext_vector_type(4))) float f32x4;

#define D_TOT 4096
#define NK    16
#define STEP  ((size_t)64 * 16 * D_TOT)   // 64 strip-slots * 16 rows * 4096

__device__ __forceinline__ short f2b(float x) {
    union { __hip_bfloat16 h; short s; } u;
    u.h = __float2bfloat16(x);
    return u.s;
}

__device__ __forceinline__ short8 cvt8(f32x4 lo, f32x4 hi) {
    short8 a;
    a[0]=f2b(lo[0]); a[1]=f2b(lo[1]); a[2]=f2b(lo[2]); a[3]=f2b(lo[3]);
    a[4]=f2b(hi[0]); a[5]=f2b(hi[1]); a[6]=f2b(hi[2]); a[7]=f2b(hi[3]);
    return a;
}

__global__ __launch_bounds__(256, 4) void block_linear_kernel(
    const float* __restrict__ inp,
    const float* __restrict__ blocks,
    float* __restrict__ out)
{
    const int tid  = threadIdx.x;
    const int wid  = blockIdx.x * 4 + (tid >> 6);   // global wave 0..4095
    const int lane = tid & 63;
    const int g    = lane >> 4;         // k-group
    const int lr   = lane & 15;         // row-within-strip / e-frag index

    const int n  = wid >> 6;            // block index (64 waves per block)
    const int s0 = wid & 63;            // strip slot; strips = s0 + 64k

    // ---- weights -> registers (one-time gather; L2/L3-hot) ----
    // frag (nt,s): lane (g,lr) holds W[d = s*32+8g+i][e = nt*16+lr], i=0..7
    const float* Wn = blocks + (size_t)n * 4096;
    short8 wf[4][2];
    #pragma unroll
    for (int nt = 0; nt < 4; ++nt)
        #pragma unroll
        for (int s = 0; s < 2; ++s) {
            short8 a;
            #pragma unroll
            for (int i = 0; i < 8; ++i)
                a[i] = f2b(Wn[(s * 32 + 8 * g + i) * 64 + nt * 16 + lr]);
            wf[nt][s] = a;
        }

    const float* gin = inp + (size_t)(s0 * 16 + lr) * D_TOT + n * 64 + 8 * g;
    float*      gout = out + (size_t)(s0 * 16 + lr) * D_TOT + n * 64 + g * 4;

    #pragma unroll 1
    for (int k = 0; k < NK; ++k) {
        const float* p = gin + (size_t)k * STEP;
        f32x4 a0 = *(const f32x4*)(p);
        f32x4 a1 = *(const f32x4*)(p + 4);
        f32x4 a2 = *(const f32x4*)(p + 32);
        f32x4 a3 = *(const f32x4*)(p + 36);

        short8 b0 = cvt8(a0, a1);       // k = 0..31 of this lane's row
        short8 b1 = cvt8(a2, a3);       // k = 32..63

        float* go = gout + (size_t)k * STEP;
        #pragma unroll
        for (int nt = 0; nt < 4; ++nt) {
            f32x4 acc = (f32x4){0.f, 0.f, 0.f, 0.f};
            acc = __builtin_amdgcn_mfma_f32_16x16x32_bf16(wf[nt][0], b0, acc, 0, 0, 0);
            acc = __builtin_amdgcn_mfma_f32_16x16x32_bf16(wf[nt][1], b1, acc, 0, 0, 0);
            // lane (g,lr) reg j -> out[row][n*64 + nt*16 + g*4 + j]
            __builtin_nontemporal_store(acc, (f32x4*)(go + nt * 16));
        }
    }
}

extern "C" void kernel_launch(void* const* d_in, const int* in_sizes, int n_in,
                              void* d_out, int out_size, void* d_ws, size_t ws_size,
                              hipStream_t stream) {
    const float* inp    = (const float*)d_in[0];
    const float* blocks = (const float*)d_in[1];
    float* out          = (float*)d_out;

    block_linear_kernel<<<1024, 256, 0, stream>>>(inp, blocks, out);
}